// Round 10
// baseline (197.984 us; speedup 1.0000x reference)
//
#include <hip/hip_runtime.h>
#include <stdint.h>

// MHA forward. I/O = fp32 (reference dtype); internal compute = bf16 MFMA.
// Pipeline (4 kernels):
//   prep:     cvt X->bf16 | transpose+cvt W_qkv (W_q pre-scaled) | W_o
//   gemm_qkv: qkv = X @ Wqkv^T  (BK=64, XOR-swizzled LDS, XCD-chunked grid;
//             V-blocks emit V^T via padded-LDS transpose)
//   attn_fwd: causal flash attention (R7 sync structure; R10: row-sums via
//             MFMA P*ones -> lacc, cvt_pk bf16 packing; no epilogue shfl)
//   gemm_o:   out = ctx @ Wo^T  (128x128 tile, XCD-chunked grid, fp32 out)
//
// Round history (rocprof-driven):
//   R1: reg-staged prefetch spilled -> staging stays global_load_lds.
//       XCD-resident attn bh map kept (FETCH 68->22->12 MB).
//   R3: __syncthreads drains vmcnt -> counted prefetch never engaged.
//   R4: raw-barrier counted vmcnt @ 12-wave occupancy = neutral.
//   R5: (512,6) VGPR cap -> spill -> 107us. R6: (512,4) fixed; occ 33%.
//   R7: loop-invariant ptrs + gemm_o 128^2; attn ~39-41us.
//   R8: attn group-dbuf = 82 KB LDS -> 1 block/CU -> 54us REGRESSION.
//       GEMM XCD swizzle = ~7us win (kept). R9 = R7 attn + R8 GEMMs: 196.5.
//   R10: attn VALU trim (VALUBusy 37% = 2.3x MfmaUtil across all rounds):
//        lsum moved to MFMA pipe (P*ones), pack via v_cvt_pk_bf16_f32.
//
// Verified layout facts (learn_hip m89/m91/m97/m120):
//   A-operand: lane holds A[m=lane&15][k=(lane>>4)*8+j], j=0..7
//   B-operand: lane holds B[k=(lane>>4)*8+j][n=lane&15]   (same map as A)
//   C/D:       col=lane&15, row=(lane>>4)*4+reg
//   global_load_lds: wave-uniform LDS base + lane*16, size=16.

typedef __attribute__((ext_vector_type(8))) short bf16x8;
typedef __attribute__((ext_vector_type(4))) float f32x4;

#define LOG2E 1.44269504088896340736f
#define QSCALE (0.125f * LOG2E) /* 1/sqrt(64) * log2(e), folded into W_q */

__device__ __forceinline__ unsigned short f2b(float f) {
  union { float f; unsigned int i; } x; x.f = f;
  unsigned int i = x.i;
  return (unsigned short)((i + 0x7FFFu + ((i >> 16) & 1u)) >> 16);
}

__device__ __forceinline__ void async16(const void* g, void* l) {
  __builtin_amdgcn_global_load_lds(
      (__attribute__((address_space(1))) void*)g,
      (__attribute__((address_space(3))) void*)l, 16, 0, 0);
}

__device__ __forceinline__ f32x4 mfma16(bf16x8 a, bf16x8 b, f32x4 c) {
  return __builtin_amdgcn_mfma_f32_16x16x32_bf16(a, b, c, 0, 0, 0);
}

__device__ __forceinline__ unsigned int fbits(float f) {
  union { float f; unsigned int i; } x; x.f = f;
  return x.i;
}

// ------------------------------------------------------------------- prep
__global__ __launch_bounds__(256) void prep(
    const float* __restrict__ X, const float* __restrict__ Wqkv,
    const float* __restrict__ Wo, unsigned short* __restrict__ Xb,
    unsigned short* __restrict__ WqkvT, unsigned short* __restrict__ WoT) {
  __shared__ __align__(16) unsigned short Lt[64 * 64];
  const int bx = blockIdx.x;
  const int t = threadIdx.x;
  if (bx < 2048) {
    const size_t i = ((size_t)bx * 256 + t) * 8;
    float4 a = *(const float4*)(X + i);
    float4 b = *(const float4*)(X + i + 4);
    unsigned short e[8];
    e[0] = f2b(a.x); e[1] = f2b(a.y); e[2] = f2b(a.z); e[3] = f2b(a.w);
    e[4] = f2b(b.x); e[5] = f2b(b.y); e[6] = f2b(b.z); e[7] = f2b(b.w);
    *(uint4*)(Xb + i) = *(const uint4*)e;
    return;
  }
  const bool is_qkv = (bx < 2816);
  const int bid = is_qkv ? bx - 2048 : bx - 2816;
  const float* src = is_qkv ? Wqkv : Wo;
  unsigned short* dst = is_qkv ? WqkvT : WoT;
  const int Ccols = is_qkv ? 3072 : 1024;
  const int r0 = (bid & 15) * 64, c0 = (bid >> 4) * 64;
  const float s = (is_qkv && c0 < 1024) ? QSCALE : 1.0f;
#pragma unroll
  for (int it = 0; it < 4; ++it) {
    int c = it * 256 + t;
    int sr = c >> 4, co = (c & 15) * 4;
    float4 v = *(const float4*)(src + (size_t)(r0 + sr) * Ccols + c0 + co);
    Lt[(co + 0) * 64 + sr] = f2b(v.x * s);
    Lt[(co + 1) * 64 + sr] = f2b(v.y * s);
    Lt[(co + 2) * 64 + sr] = f2b(v.z * s);
    Lt[(co + 3) * 64 + sr] = f2b(v.w * s);
  }
  __syncthreads();
#pragma unroll
  for (int it = 0; it < 2; ++it) {
    int c = it * 256 + t;
    int dr = c >> 3, so = (c & 7) * 8;
    *(uint4*)(dst + (size_t)(c0 + dr) * 1024 + r0 + so) =
        *(const uint4*)(Lt + dr * 64 + so);
  }
}

// ---------------------------------------------------------------- gemm_qkv
// 128x128 tile, BK=64, XOR-swizzled LDS, XCD-chunked grid (R8: ~7us win —
// each XCD owns 4 full m-rows x 24 n: A panels 1 MB fully L2-resident).
__global__ __launch_bounds__(256) void gemm_qkv(
    const unsigned short* __restrict__ A, const unsigned short* __restrict__ Bt,
    unsigned short* __restrict__ C, unsigned short* __restrict__ Vt) {
  constexpr int K = 1024, N = 3072;
  __shared__ __align__(16) unsigned short Sm[16896];  // 33792 B
  unsigned short* As = Sm;          // 128*64
  unsigned short* Bs = Sm + 8192;   // 128*64
  unsigned short* Lt = Sm;          // 128*132 (epilogue only)

  const int t = threadIdx.x;
  const int w = t >> 6, l = t & 63;
  // bijective XCD chunk swizzle: 768 blocks, 96 per XCD
  const int flat = blockIdx.x + 24 * blockIdx.y;
  const int swz = (flat & 7) * 96 + (flat >> 3);
  const int m0 = (swz / 24) * 128, n0 = (swz % 24) * 128;
  const int wm = (w >> 1) * 64, wn = (w & 1) * 64;
  const int lrow = l & 15, lq = l >> 4;

  f32x4 acc[4][4] = {};

  for (int k0 = 0; k0 < K; k0 += 64) {
    __syncthreads();
#pragma unroll
    for (int r = 0; r < 4; ++r) {
      const int c = r * 256 + t;
      const int row = c >> 3;
      const int so = ((c & 7) ^ (row & 7)) * 8;
      async16(A + (size_t)(m0 + row) * K + k0 + so,
              As + (size_t)(r * 256 + t) * 8);
      async16(Bt + (size_t)(n0 + row) * K + k0 + so,
              Bs + (size_t)(r * 256 + t) * 8);
    }
    asm volatile("s_waitcnt vmcnt(0)" ::: "memory");
    __syncthreads();

#pragma unroll
    for (int kh = 0; kh < 2; ++kh) {
      bf16x8 af[4], bf[4];
      const int phys = ((kh * 4 + lq) ^ (lrow & 7)) * 8;
#pragma unroll
      for (int i = 0; i < 4; ++i)
        af[i] = *(const bf16x8*)(As + (wm + i * 16 + lrow) * 64 + phys);
#pragma unroll
      for (int j = 0; j < 4; ++j)
        bf[j] = *(const bf16x8*)(Bs + (wn + j * 16 + lrow) * 64 + phys);
#pragma unroll
      for (int i = 0; i < 4; ++i)
#pragma unroll
        for (int j = 0; j < 4; ++j)
          acc[i][j] = mfma16(af[i], bf[j], acc[i][j]);
    }
  }

  if (n0 < 2048) {  // Q/K blocks: plain store into qkv
#pragma unroll
    for (int i = 0; i < 4; ++i)
#pragma unroll
      for (int j = 0; j < 4; ++j)
#pragma unroll
        for (int r = 0; r < 4; ++r) {
          int gr = m0 + wm + i * 16 + lq * 4 + r;
          int gc = n0 + wn + j * 16 + lrow;
          C[(size_t)gr * N + gc] = f2b(acc[i][j][r]);
        }
  } else {  // V blocks: transpose through padded LDS -> coalesced Vt stores
    __syncthreads();  // all waves done reading As/Bs
#pragma unroll
    for (int i = 0; i < 4; ++i)
#pragma unroll
      for (int j = 0; j < 4; ++j) {
        int col_loc = wn + j * 16 + lrow;   // V column within tile
        int row_loc = wm + i * 16 + lq * 4; // token within tile
        uint2 pk;
        pk.x = (unsigned int)f2b(acc[i][j][0]) |
               ((unsigned int)f2b(acc[i][j][1]) << 16);
        pk.y = (unsigned int)f2b(acc[i][j][2]) |
               ((unsigned int)f2b(acc[i][j][3]) << 16);
        *(uint2*)(Lt + col_loc * 132 + row_loc) = pk;
      }
    __syncthreads();
    const int b = m0 >> 11, s0 = m0 & 2047;
    const int vb0 = n0 - 2048;
#pragma unroll
    for (int rnd = 0; rnd < 8; ++rnd) {
      int vrow = rnd * 16 + (t >> 4);  // V col within tile
      int sloc = (t & 15) * 8;
      int vcol = vb0 + vrow;
      int bh = b * 16 + (vcol >> 6);
      int d = vcol & 63;
      *(uint4*)(Vt + ((size_t)bh * 64 + d) * 2048 + s0 + sloc) =
          *(const uint4*)(Lt + vrow * 132 + sloc);
    }
  }
}

// ------------------------- out-proj GEMM: 128x128 tile, BK=64, XCD-chunked
__global__ __launch_bounds__(256) void gemm_o(
    const unsigned short* __restrict__ A, const unsigned short* __restrict__ Bt,
    float* __restrict__ C, int M, int N, int K) {
  __shared__ __align__(16) unsigned short As[128 * 64];
  __shared__ __align__(16) unsigned short Bs[128 * 64];
  const int t = threadIdx.x;
  const int w = t >> 6, l = t & 63;
  // bijective XCD chunk swizzle: 256 blocks, 32 per XCD (A 1MB + B 2MB resident)
  const int flat = blockIdx.x + 8 * blockIdx.y;
  const int swz = (flat & 7) * 32 + (flat >> 3);
  const int m0 = (swz >> 3) * 128, n0 = (swz & 7) * 128;
  const int wm = (w >> 1) * 64, wn = (w & 1) * 64;
  const int lrow = l & 15, lq = l >> 4;

  f32x4 acc[4][4] = {};

  for (int k0 = 0; k0 < K; k0 += 64) {
    __syncthreads();
#pragma unroll
    for (int r = 0; r < 4; ++r) {
      const int c = r * 256 + t;
      const int row = c >> 3;
      const int so = ((c & 7) ^ (row & 7)) * 8;
      async16(A + (size_t)(m0 + row) * K + k0 + so,
              As + (size_t)(r * 256 + t) * 8);
      async16(Bt + (size_t)(n0 + row) * K + k0 + so,
              Bs + (size_t)(r * 256 + t) * 8);
    }
    asm volatile("s_waitcnt vmcnt(0)" ::: "memory");
    __syncthreads();

#pragma unroll
    for (int kh = 0; kh < 2; ++kh) {
      bf16x8 af[4], bf[4];
      const int phys = ((kh * 4 + lq) ^ (lrow & 7)) * 8;
#pragma unroll
      for (int i = 0; i < 4; ++i)
        af[i] = *(const bf16x8*)(As + (wm + i * 16 + lrow) * 64 + phys);
#pragma unroll
      for (int j = 0; j < 4; ++j)
        bf[j] = *(const bf16x8*)(Bs + (wn + j * 16 + lrow) * 64 + phys);
#pragma unroll
      for (int i = 0; i < 4; ++i)
#pragma unroll
        for (int j = 0; j < 4; ++j)
          acc[i][j] = mfma16(af[i], bf[j], acc[i][j]);
    }
  }

#pragma unroll
  for (int i = 0; i < 4; ++i)
#pragma unroll
    for (int j = 0; j < 4; ++j)
#pragma unroll
      for (int r = 0; r < 4; ++r) {
        int gr = m0 + wm + i * 16 + lq * 4 + r;
        int gc = n0 + wn + j * 16 + lrow;
        C[(size_t)gr * N + gc] = acc[i][j][r];
      }
}

// ---------------------------------------------------------------- attention
// R10 = R9 sync structure; VALU softmax trimmed:
//  - row sums via MFMA: lacc = P*ones (B-frag of bf16 1.0). C-layout puts
//    lsum[q=w*16+lq*4+r] in lacc[r] — exactly the index the final divide
//    needs, so the epilogue shfl reduction disappears entirely.
//  - P->bf16 pack via v_cvt_pk_bf16_f32 (2 insts/uint2, was 6; RNE).
// Grid (32 bh, 32 ti): xcd = bh&7; ti = 31-blockIdx.y heavy-first.
// LDS 50 KB -> 3 blocks/CU. (512,4): VGPR cap 128 (R5 lesson).
__global__ __launch_bounds__(512, 4) void attn_fwd(
    const unsigned short* __restrict__ qkv,
    const unsigned short* __restrict__ Vt,
    unsigned short* __restrict__ ctx) {
  __shared__ __align__(16) unsigned short Ks[2][64 * 64];
  __shared__ __align__(16) unsigned short Vs[2][64 * 64];
  __shared__ __align__(16) unsigned short Ps[8][16 * 72];

  const int bh = blockIdx.x;       // xcd = bh & 7 (L2 residency)
  const int ti = 31 - blockIdx.y;  // heavy-first
  const int b = bh >> 4, h = bh & 15;
  const int t = threadIdx.x;
  const int g = t >> 8;    // kv-group
  const int tl = t & 255;  // id within group
  const int w = tl >> 6;   // wave within group = q row strip
  const int gw = t >> 6;   // global wave id (P buffer)
  const int l = t & 63;
  const int lm = l & 15, lq = l >> 4;
  const int sw = lm & 7;
  const int c0 = (lq ^ sw) * 8;
  const int c1 = ((lq + 4) ^ sw) * 8;

  const unsigned short* Qp = qkv + (size_t)(b * 2048) * 3072 + h * 64;
  const unsigned short* Kp = qkv + (size_t)(b * 2048) * 3072 + 1024 + h * 64;
  const unsigned short* Vb = Vt + (size_t)bh * 64 * 2048;

  const int qrow = ti * 64 + w * 16 + lm;
  bf16x8 qf0 = *(const bf16x8*)(Qp + (size_t)qrow * 3072 + lq * 8);
  bf16x8 qf1 = *(const bf16x8*)(Qp + (size_t)qrow * 3072 + 32 + lq * 8);

  // B-fragment of bf16 1.0 for lsum-via-MFMA
  bf16x8 vones;
#pragma unroll
  for (int j = 0; j < 8; ++j) vones[j] = (short)0x3F80;

  // loop-invariant staging addresses (R7)
  const int srow = tl >> 3, scp = tl & 7;
  const int sso = (scp ^ (srow & 7)) * 8;  // (srow+32)&7 == srow&7
  const unsigned short* kp0 = Kp + (size_t)(g * 64 + srow) * 3072 + sso;
  const unsigned short* kp1 = kp0 + (size_t)32 * 3072;
  const unsigned short* vp0 = Vb + (size_t)srow * 2048 + g * 64 + sso;
  const unsigned short* vp1 = vp0 + (size_t)32 * 2048;
  unsigned short* kd0 = Ks[g] + (size_t)(w * 64) * 8;
  unsigned short* kd1 = Ks[g] + (size_t)(256 + w * 64) * 8;
  unsigned short* vd0 = Vs[g] + (size_t)(w * 64) * 8;
  unsigned short* vd1 = Vs[g] + (size_t)(256 + w * 64) * 8;

  f32x4 oacc[4] = {};
  f32x4 lacc = {};  // lacc[r] = sum_kv P[q = w*16+lq*4+r][kv]

  const int nsup = (ti >> 1) + 1;  // supersteps: kt = 2*jj + g <= ti

  for (int jj = 0; jj < nsup; ++jj) {
    const int kt = 2 * jj + g;
    const bool have = (kt <= ti);
    __syncthreads();  // protect group buffers from overwrite
    if (have) {
      async16(kp0, kd0);
      async16(vp0, vd0);
      async16(kp1, kd1);
      async16(vp1, vd1);
    }
    kp0 += 128 * 3072; kp1 += 128 * 3072;  // 2 tiles ahead (group stride)
    vp0 += 128; vp1 += 128;
    asm volatile("s_waitcnt vmcnt(0)" ::: "memory");
    __syncthreads();
    if (!have) continue;

    const unsigned short* Kc = Ks[g];
    const unsigned short* Vc = Vs[g];

    // hoist V fragments: vf[ks*4+nt] (overlaps with softmax VALU)
    bf16x8 vf[8];
#pragma unroll
    for (int nt = 0; nt < 4; ++nt) {
      const unsigned short* vr = Vc + (nt * 16 + lm) * 64;
      vf[nt] = *(const bf16x8*)(vr + c0);
      vf[4 + nt] = *(const bf16x8*)(vr + c1);
    }

    // S^T = K Q^T : lane holds q = lm, kv = mt*16 + lq*4 + r
    f32x4 sacc[4] = {};
    __builtin_amdgcn_s_setprio(1);
#pragma unroll
    for (int mt = 0; mt < 4; ++mt) {
      const unsigned short* kr = Kc + (mt * 16 + lm) * 64;
      bf16x8 bk0 = *(const bf16x8*)(kr + c0);
      bf16x8 bk1 = *(const bf16x8*)(kr + c1);
      sacc[mt] = mfma16(bk0, qf0, sacc[mt]);
      sacc[mt] = mfma16(bk1, qf1, sacc[mt]);
    }
    __builtin_amdgcn_s_setprio(0);

    const bool diag = (kt == ti);
    const int qloc = w * 16 + lm;
#pragma unroll
    for (int mt = 0; mt < 4; ++mt) {
      float p0 = __builtin_amdgcn_exp2f(sacc[mt][0]);
      float p1 = __builtin_amdgcn_exp2f(sacc[mt][1]);
      float p2 = __builtin_amdgcn_exp2f(sacc[mt][2]);
      float p3 = __builtin_amdgcn_exp2f(sacc[mt][3]);
      if (diag) {
        const int kvb = mt * 16 + lq * 4;
        if (kvb + 0 > qloc) p0 = 0.f;
        if (kvb + 1 > qloc) p1 = 0.f;
        if (kvb + 2 > qloc) p2 = 0.f;
        if (kvb + 3 > qloc) p3 = 0.f;
      }
      uint2 pk;
      asm("v_cvt_pk_bf16_f32 %0, %1, %2" : "=v"(pk.x) : "v"(p0), "v"(p1));
      asm("v_cvt_pk_bf16_f32 %0, %1, %2" : "=v"(pk.y) : "v"(p2), "v"(p3));
      *(uint2*)(&Ps[gw][lm * 72 + mt * 16 + lq * 4]) = pk;
    }
    asm volatile("s_waitcnt lgkmcnt(0)" ::: "memory");

    // O += P V ; lacc += P * ones  (row sums on the MFMA pipe)
    __builtin_amdgcn_s_setprio(1);
#pragma unroll
    for (int ks = 0; ks < 2; ++ks) {
      bf16x8 pa = *(const bf16x8*)(&Ps[gw][lm * 72 + ks * 32 + lq * 8]);
#pragma unroll
      for (int nt = 0; nt < 4; ++nt)
        oacc[nt] = mfma16(pa, vf[ks * 4 + nt], oacc[nt]);
      lacc = mfma16(pa, vones, lacc);
    }
    __builtin_amdgcn_s_setprio(0);
  }

  // cross-group combine: group 1 parks partials in LDS, group 0 finalizes.
  // lacc[r] already holds lsum for q-row w*16+lq*4+r — no shuffles needed.
  __syncthreads();
  float* fbuf = (float*)Ks;  // 64x64 fp32 = 16 KB (Ks block is 16 KB)
  float* lbuf = (float*)Ps;  // 64 fp32, indexed by q-row
  if (g == 1) {
#pragma unroll
    for (int nt = 0; nt < 4; ++nt)
#pragma unroll
      for (int r = 0; r < 4; ++r)
        fbuf[(w * 16 + lq * 4 + r) * 64 + nt * 16 + lm] = oacc[nt][r];
    if (lm == 0) {
#pragma unroll
      for (int r = 0; r < 4; ++r) lbuf[w * 16 + lq * 4 + r] = lacc[r];
    }
  }
  __syncthreads();
  if (g == 0) {
    float rinv[4];
#pragma unroll
    for (int r = 0; r < 4; ++r)
      rinv[r] = 1.f / (lacc[r] + lbuf[w * 16 + lq * 4 + r]);
#pragma unroll
    for (int nt = 0; nt < 4; ++nt)
#pragma unroll
      for (int r = 0; r < 4; ++r) {
        float v = oacc[nt][r] +
                  fbuf[(w * 16 + lq * 4 + r) * 64 + nt * 16 + lm];
        size_t tok = (size_t)b * 2048 + ti * 64 + w * 16 + lq * 4 + r;
        ctx[tok * 1024 + h * 64 + nt * 16 + lm] = f2b(v * rinv[r]);
      }
  }
}

// ---------------------------------------------------------------- launch
extern "C" void kernel_launch(void* const* d_in, const int* in_sizes, int n_in,
                              void* d_out, int out_size, void* d_ws,
                              size_t ws_size, hipStream_t stream) {
  const float* query = (const float*)d_in[0];
  // d_in[1] key, d_in[2] value: unused by reference. d_in[3] mask: causal
  // tril, applied analytically.
  const float* w_qkv = (const float*)d_in[4];
  const float* w_o = (const float*)d_in[5];
  float* out = (float*)d_out;

  unsigned short* ws = (unsigned short*)d_ws;
  unsigned short* wqkvT = ws;                               // 3072*1024
  unsigned short* woT = wqkvT + (size_t)3072 * 1024;        // 1024*1024
  unsigned short* Xb = woT + (size_t)1024 * 1024;           // 4096*1024
  unsigned short* qkv = Xb + (size_t)4096 * 1024;           // 4096*3072 (Q,K)
  unsigned short* Vt = qkv + (size_t)4096 * 3072;           // 32*64*2048
  unsigned short* ctx = Xb;  // Xb dead after gemm_qkv -> reuse for ctx
  // total: 48 MB of d_ws

  prep<<<dim3(3072), 256, 0, stream>>>(query, w_qkv, w_o, Xb, wqkvT, woT);
  gemm_qkv<<<dim3(24, 32), 256, 0, stream>>>(Xb, wqkvT, qkv, Vt);
  attn_fwd<<<dim3(32, 32), 512, 0, stream>>>(qkv, Vt, ctx);
  gemm_o<<<dim3(8, 32), 256, 0, stream>>>(ctx, woT, out, 4096, 1024, 1024);
}

// Round 12
// 196.327 us; speedup vs baseline: 1.0084x; 1.0084x over previous
//
#include <hip/hip_runtime.h>
#include <stdint.h>

// MHA forward. I/O = fp32 (reference dtype); internal compute = bf16 MFMA.
// Pipeline (4 kernels):
//   prep:     cvt X->bf16 | transpose+cvt W_qkv (W_q pre-scaled) | W_o
//   gemm_qkv: qkv = X @ Wqkv^T  (BK=64, XOR-swizzled LDS, XCD-chunked grid;
//             V-blocks emit V^T via padded-LDS transpose)
//   attn_fwd: causal flash attention. R11: QBLK=32 per wave (K/V fragment
//             reads amortized over 2 q-halves -> LDS-pipe ops/work -36%).
//             256-thr block = 2 kv-groups x 2 waves; same grid/LDS/sync.
//   gemm_o:   out = ctx @ Wo^T  (128x128 tile, XCD-chunked grid, fp32 out)
//
// Round history (rocprof-driven):
//   R1: reg-staged prefetch spilled -> staging stays global_load_lds.
//   R3: __syncthreads drains vmcnt -> counted prefetch never engaged.
//   R4: raw-barrier counted vmcnt = neutral (loads L2-hit, TLP-hidden).
//   R5: (512,6) VGPR cap -> spill -> 107us. R6: (512,4) fixed.
//   R7: loop-invariant staging ptrs. R8: attn dbuf 82KB LDS -> 1 blk/CU
//       regression; GEMM XCD chunk swizzle ~7us win (kept).
//   R9: best total 196.5 (R7 attn + R8 GEMMs). R10: VALU trim neutral ->
//       instruction count NOT binding. R2~R6 wave-count invariance + R10
//       null => LDS pipe saturated (16 b128/superstep/wave; ~60% of cycle
//       budget at m134's 12cyc/b128). R11: halve K/V reads per work unit.
//   R11 bench attempt 1: container infra failure (no data); kernel
//       re-audited (staging algebra, LDS bounds, lane-linearity) — resubmit.
//
// Verified layout facts (learn_hip m89/m91/m97/m120):
//   A-operand: lane holds A[m=lane&15][k=(lane>>4)*8+j], j=0..7
//   B-operand: lane holds B[k=(lane>>4)*8+j][n=lane&15]   (same map as A)
//   C/D:       col=lane&15, row=(lane>>4)*4+reg
//   global_load_lds: wave-uniform LDS base + lane*16, size=16.

typedef __attribute__((ext_vector_type(8))) short bf16x8;
typedef __attribute__((ext_vector_type(4))) float f32x4;

#define LOG2E 1.44269504088896340736f
#define QSCALE (0.125f * LOG2E) /* 1/sqrt(64) * log2(e), folded into W_q */

__device__ __forceinline__ unsigned short f2b(float f) {
  union { float f; unsigned int i; } x; x.f = f;
  unsigned int i = x.i;
  return (unsigned short)((i + 0x7FFFu + ((i >> 16) & 1u)) >> 16);
}

__device__ __forceinline__ void async16(const void* g, void* l) {
  __builtin_amdgcn_global_load_lds(
      (__attribute__((address_space(1))) void*)g,
      (__attribute__((address_space(3))) void*)l, 16, 0, 0);
}

__device__ __forceinline__ f32x4 mfma16(bf16x8 a, bf16x8 b, f32x4 c) {
  return __builtin_amdgcn_mfma_f32_16x16x32_bf16(a, b, c, 0, 0, 0);
}

__device__ __forceinline__ unsigned int fbits(float f) {
  union { float f; unsigned int i; } x; x.f = f;
  return x.i;
}

// ------------------------------------------------------------------- prep
__global__ __launch_bounds__(256) void prep(
    const float* __restrict__ X, const float* __restrict__ Wqkv,
    const float* __restrict__ Wo, unsigned short* __restrict__ Xb,
    unsigned short* __restrict__ WqkvT, unsigned short* __restrict__ WoT) {
  __shared__ __align__(16) unsigned short Lt[64 * 64];
  const int bx = blockIdx.x;
  const int t = threadIdx.x;
  if (bx < 2048) {
    const size_t i = ((size_t)bx * 256 + t) * 8;
    float4 a = *(const float4*)(X + i);
    float4 b = *(const float4*)(X + i + 4);
    unsigned short e[8];
    e[0] = f2b(a.x); e[1] = f2b(a.y); e[2] = f2b(a.z); e[3] = f2b(a.w);
    e[4] = f2b(b.x); e[5] = f2b(b.y); e[6] = f2b(b.z); e[7] = f2b(b.w);
    *(uint4*)(Xb + i) = *(const uint4*)e;
    return;
  }
  const bool is_qkv = (bx < 2816);
  const int bid = is_qkv ? bx - 2048 : bx - 2816;
  const float* src = is_qkv ? Wqkv : Wo;
  unsigned short* dst = is_qkv ? WqkvT : WoT;
  const int Ccols = is_qkv ? 3072 : 1024;
  const int r0 = (bid & 15) * 64, c0 = (bid >> 4) * 64;
  const float s = (is_qkv && c0 < 1024) ? QSCALE : 1.0f;
#pragma unroll
  for (int it = 0; it < 4; ++it) {
    int c = it * 256 + t;
    int sr = c >> 4, co = (c & 15) * 4;
    float4 v = *(const float4*)(src + (size_t)(r0 + sr) * Ccols + c0 + co);
    Lt[(co + 0) * 64 + sr] = f2b(v.x * s);
    Lt[(co + 1) * 64 + sr] = f2b(v.y * s);
    Lt[(co + 2) * 64 + sr] = f2b(v.z * s);
    Lt[(co + 3) * 64 + sr] = f2b(v.w * s);
  }
  __syncthreads();
#pragma unroll
  for (int it = 0; it < 2; ++it) {
    int c = it * 256 + t;
    int dr = c >> 3, so = (c & 7) * 8;
    *(uint4*)(dst + (size_t)(c0 + dr) * 1024 + r0 + so) =
        *(const uint4*)(Lt + dr * 64 + so);
  }
}

// ---------------------------------------------------------------- gemm_qkv
// 128x128 tile, BK=64, XOR-swizzled LDS, XCD-chunked grid (R8: ~7us win).
__global__ __launch_bounds__(256) void gemm_qkv(
    const unsigned short* __restrict__ A, const unsigned short* __restrict__ Bt,
    unsigned short* __restrict__ C, unsigned short* __restrict__ Vt) {
  constexpr int K = 1024, N = 3072;
  __shared__ __align__(16) unsigned short Sm[16896];  // 33792 B
  unsigned short* As = Sm;          // 128*64
  unsigned short* Bs = Sm + 8192;   // 128*64
  unsigned short* Lt = Sm;          // 128*132 (epilogue only)

  const int t = threadIdx.x;
  const int w = t >> 6, l = t & 63;
  // bijective XCD chunk swizzle: 768 blocks, 96 per XCD
  const int flat = blockIdx.x + 24 * blockIdx.y;
  const int swz = (flat & 7) * 96 + (flat >> 3);
  const int m0 = (swz / 24) * 128, n0 = (swz % 24) * 128;
  const int wm = (w >> 1) * 64, wn = (w & 1) * 64;
  const int lrow = l & 15, lq = l >> 4;

  f32x4 acc[4][4] = {};

  for (int k0 = 0; k0 < K; k0 += 64) {
    __syncthreads();
#pragma unroll
    for (int r = 0; r < 4; ++r) {
      const int c = r * 256 + t;
      const int row = c >> 3;
      const int so = ((c & 7) ^ (row & 7)) * 8;
      async16(A + (size_t)(m0 + row) * K + k0 + so,
              As + (size_t)(r * 256 + t) * 8);
      async16(Bt + (size_t)(n0 + row) * K + k0 + so,
              Bs + (size_t)(r * 256 + t) * 8);
    }
    asm volatile("s_waitcnt vmcnt(0)" ::: "memory");
    __syncthreads();

#pragma unroll
    for (int kh = 0; kh < 2; ++kh) {
      bf16x8 af[4], bf[4];
      const int phys = ((kh * 4 + lq) ^ (lrow & 7)) * 8;
#pragma unroll
      for (int i = 0; i < 4; ++i)
        af[i] = *(const bf16x8*)(As + (wm + i * 16 + lrow) * 64 + phys);
#pragma unroll
      for (int j = 0; j < 4; ++j)
        bf[j] = *(const bf16x8*)(Bs + (wn + j * 16 + lrow) * 64 + phys);
#pragma unroll
      for (int i = 0; i < 4; ++i)
#pragma unroll
        for (int j = 0; j < 4; ++j)
          acc[i][j] = mfma16(af[i], bf[j], acc[i][j]);
    }
  }

  if (n0 < 2048) {  // Q/K blocks: plain store into qkv
#pragma unroll
    for (int i = 0; i < 4; ++i)
#pragma unroll
      for (int j = 0; j < 4; ++j)
#pragma unroll
        for (int r = 0; r < 4; ++r) {
          int gr = m0 + wm + i * 16 + lq * 4 + r;
          int gc = n0 + wn + j * 16 + lrow;
          C[(size_t)gr * N + gc] = f2b(acc[i][j][r]);
        }
  } else {  // V blocks: transpose through padded LDS -> coalesced Vt stores
    __syncthreads();  // all waves done reading As/Bs
#pragma unroll
    for (int i = 0; i < 4; ++i)
#pragma unroll
      for (int j = 0; j < 4; ++j) {
        int col_loc = wn + j * 16 + lrow;   // V column within tile
        int row_loc = wm + i * 16 + lq * 4; // token within tile
        uint2 pk;
        pk.x = (unsigned int)f2b(acc[i][j][0]) |
               ((unsigned int)f2b(acc[i][j][1]) << 16);
        pk.y = (unsigned int)f2b(acc[i][j][2]) |
               ((unsigned int)f2b(acc[i][j][3]) << 16);
        *(uint2*)(Lt + col_loc * 132 + row_loc) = pk;
      }
    __syncthreads();
    const int b = m0 >> 11, s0 = m0 & 2047;
    const int vb0 = n0 - 2048;
#pragma unroll
    for (int rnd = 0; rnd < 8; ++rnd) {
      int vrow = rnd * 16 + (t >> 4);  // V col within tile
      int sloc = (t & 15) * 8;
      int vcol = vb0 + vrow;
      int bh = b * 16 + (vcol >> 6);
      int d = vcol & 63;
      *(uint4*)(Vt + ((size_t)bh * 64 + d) * 2048 + s0 + sloc) =
          *(const uint4*)(Lt + vrow * 132 + sloc);
    }
  }
}

// ------------------------- out-proj GEMM: 128x128 tile, BK=64, XCD-chunked
__global__ __launch_bounds__(256) void gemm_o(
    const unsigned short* __restrict__ A, const unsigned short* __restrict__ Bt,
    float* __restrict__ C, int M, int N, int K) {
  __shared__ __align__(16) unsigned short As[128 * 64];
  __shared__ __align__(16) unsigned short Bs[128 * 64];
  const int t = threadIdx.x;
  const int w = t >> 6, l = t & 63;
  // bijective XCD chunk swizzle: 256 blocks, 32 per XCD
  const int flat = blockIdx.x + 8 * blockIdx.y;
  const int swz = (flat & 7) * 32 + (flat >> 3);
  const int m0 = (swz >> 3) * 128, n0 = (swz & 7) * 128;
  const int wm = (w >> 1) * 64, wn = (w & 1) * 64;
  const int lrow = l & 15, lq = l >> 4;

  f32x4 acc[4][4] = {};

  for (int k0 = 0; k0 < K; k0 += 64) {
    __syncthreads();
#pragma unroll
    for (int r = 0; r < 4; ++r) {
      const int c = r * 256 + t;
      const int row = c >> 3;
      const int so = ((c & 7) ^ (row & 7)) * 8;
      async16(A + (size_t)(m0 + row) * K + k0 + so,
              As + (size_t)(r * 256 + t) * 8);
      async16(Bt + (size_t)(n0 + row) * K + k0 + so,
              Bs + (size_t)(r * 256 + t) * 8);
    }
    asm volatile("s_waitcnt vmcnt(0)" ::: "memory");
    __syncthreads();

#pragma unroll
    for (int kh = 0; kh < 2; ++kh) {
      bf16x8 af[4], bf[4];
      const int phys = ((kh * 4 + lq) ^ (lrow & 7)) * 8;
#pragma unroll
      for (int i = 0; i < 4; ++i)
        af[i] = *(const bf16x8*)(As + (wm + i * 16 + lrow) * 64 + phys);
#pragma unroll
      for (int j = 0; j < 4; ++j)
        bf[j] = *(const bf16x8*)(Bs + (wn + j * 16 + lrow) * 64 + phys);
#pragma unroll
      for (int i = 0; i < 4; ++i)
#pragma unroll
        for (int j = 0; j < 4; ++j)
          acc[i][j] = mfma16(af[i], bf[j], acc[i][j]);
    }
  }

#pragma unroll
  for (int i = 0; i < 4; ++i)
#pragma unroll
    for (int j = 0; j < 4; ++j)
#pragma unroll
      for (int r = 0; r < 4; ++r) {
        int gr = m0 + wm + i * 16 + lq * 4 + r;
        int gc = n0 + wn + j * 16 + lrow;
        C[(size_t)gr * N + gc] = acc[i][j][r];
      }
}

// ---------------------------------------------------------------- attention
// R11: 256 threads = 2 kv-groups x 2 waves; each wave covers 32 q-rows
// (two 16-row halves qh=0,1) of the block's 64-row q-tile. K fragments are
// read ONCE per mt and feed both qh MFMAs; V fragments read ONCE per
// (ks,nt) feeding both qh -> LDS ops per unit work drop 36% (LDS pipe was
// the saturated resource: R2~R6 wave-count invariance + R10 VALU-trim null
// + 16 b128/superstep/wave ~ 60% of cycle budget at 12cyc/b128).
// Grid (32 bh, 32 ti): xcd = bh&7; ti = 31-blockIdx.y heavy-first.
// LDS 51200 B (Ks/Vs 32K + Ps[4][2] 18.4K) -> 3 blocks/CU = 12 waves.
// launch_bounds(256,3): VGPR cap ~170 (live ~120, no spill; R5 lesson).
__global__ __launch_bounds__(256, 3) void attn_fwd(
    const unsigned short* __restrict__ qkv,
    const unsigned short* __restrict__ Vt,
    unsigned short* __restrict__ ctx) {
  __shared__ __align__(16) unsigned short Ks[2][64 * 64];
  __shared__ __align__(16) unsigned short Vs[2][64 * 64];
  __shared__ __align__(16) unsigned short Ps[4][2][16 * 72];

  const int bh = blockIdx.x;       // xcd = bh & 7 (L2 residency)
  const int ti = 31 - blockIdx.y;  // heavy-first
  const int b = bh >> 4, h = bh & 15;
  const int t = threadIdx.x;
  const int g = t >> 7;        // kv-group (2 waves each)
  const int gl = t & 127;      // id within group
  const int w = t >> 6;        // wave id 0..3
  const int qs = (w & 1) * 32; // wave's 32-row q-strip within the tile
  const int l = t & 63;
  const int lm = l & 15, lq = l >> 4;
  const int sw = lm & 7;
  const int c0 = (lq ^ sw) * 8;
  const int c1 = ((lq + 4) ^ sw) * 8;

  const unsigned short* Qp = qkv + (size_t)(b * 2048) * 3072 + h * 64;
  const unsigned short* Kp = qkv + (size_t)(b * 2048) * 3072 + 1024 + h * 64;
  const unsigned short* Vb = Vt + (size_t)bh * 64 * 2048;

  // Q fragments for both 16-row halves of this wave's strip
  bf16x8 qf[2][2];
#pragma unroll
  for (int qh = 0; qh < 2; ++qh) {
    const int qrow = ti * 64 + qs + qh * 16 + lm;
    qf[qh][0] = *(const bf16x8*)(Qp + (size_t)qrow * 3072 + lq * 8);
    qf[qh][1] = *(const bf16x8*)(Qp + (size_t)qrow * 3072 + 32 + lq * 8);
  }

  // B-fragment of bf16 1.0 for lsum-via-MFMA
  bf16x8 vones;
#pragma unroll
  for (int j = 0; j < 8; ++j) vones[j] = (short)0x3F80;

  // staging: 4 passes of 16 rows each for K and V (8 async16/thread)
  const int srow = gl >> 3, scp = gl & 7;
  const int sso = (scp ^ (srow & 7)) * 8;  // pass-invariant (16 = 0 mod 8)
  const unsigned short* kb = Kp + (size_t)srow * 3072 + sso;
  const unsigned short* vbp = Vb + (size_t)srow * 2048 + sso;
  unsigned short* kdst = Ks[g] + (size_t)gl * 8;  // + p*1024 per pass
  unsigned short* vdst = Vs[g] + (size_t)gl * 8;
  size_t koff = (size_t)(g * 64) * 3072;  // element offset for kt = g
  size_t voff = (size_t)(g * 64);

  f32x4 oacc[2][4] = {};
  f32x4 lacc[2] = {};  // lacc[qh][r] = lsum[q = qs + qh*16 + lq*4 + r]

  const int nsup = (ti >> 1) + 1;  // supersteps: kt = 2*jj + g <= ti

  for (int jj = 0; jj < nsup; ++jj) {
    const int kt = 2 * jj + g;
    const bool have = (kt <= ti);
    __syncthreads();  // protect group buffers from overwrite
    if (have) {
#pragma unroll
      for (int p = 0; p < 4; ++p) {
        async16(kb + koff + (size_t)(p * 16) * 3072, kdst + p * 1024);
        async16(vbp + voff + (size_t)(p * 16) * 2048, vdst + p * 1024);
      }
    }
    koff += (size_t)128 * 3072;  // group stride = 2 tiles
    voff += 128;
    asm volatile("s_waitcnt vmcnt(0)" ::: "memory");
    __syncthreads();
    if (!have) continue;

    const unsigned short* Kc = Ks[g];
    const unsigned short* Vc = Vs[g];

    // S^T = K Q^T for both q-halves; K fragments read ONCE per mt.
    // lane holds S[kv = mt*16 + lq*4 + r][q = qs + qh*16 + lm]
    f32x4 sacc[2][4] = {};
    __builtin_amdgcn_s_setprio(1);
#pragma unroll
    for (int mt = 0; mt < 4; ++mt) {
      const unsigned short* kr = Kc + (mt * 16 + lm) * 64;
      bf16x8 bk0 = *(const bf16x8*)(kr + c0);
      bf16x8 bk1 = *(const bf16x8*)(kr + c1);
      sacc[0][mt] = mfma16(bk0, qf[0][0], sacc[0][mt]);
      sacc[0][mt] = mfma16(bk1, qf[0][1], sacc[0][mt]);
      sacc[1][mt] = mfma16(bk0, qf[1][0], sacc[1][mt]);
      sacc[1][mt] = mfma16(bk1, qf[1][1], sacc[1][mt]);
    }
    __builtin_amdgcn_s_setprio(0);

    const bool diag = (kt == ti);
#pragma unroll
    for (int qh = 0; qh < 2; ++qh) {
      const int qloc = qs + qh * 16 + lm;
#pragma unroll
      for (int mt = 0; mt < 4; ++mt) {
        float p0 = __builtin_amdgcn_exp2f(sacc[qh][mt][0]);
        float p1 = __builtin_amdgcn_exp2f(sacc[qh][mt][1]);
        float p2 = __builtin_amdgcn_exp2f(sacc[qh][mt][2]);
        float p3 = __builtin_amdgcn_exp2f(sacc[qh][mt][3]);
        if (diag) {
          const int kvb = mt * 16 + lq * 4;
          if (kvb + 0 > qloc) p0 = 0.f;
          if (kvb + 1 > qloc) p1 = 0.f;
          if (kvb + 2 > qloc) p2 = 0.f;
          if (kvb + 3 > qloc) p3 = 0.f;
        }
        uint2 pk;
        asm("v_cvt_pk_bf16_f32 %0, %1, %2" : "=v"(pk.x) : "v"(p0), "v"(p1));
        asm("v_cvt_pk_bf16_f32 %0, %1, %2" : "=v"(pk.y) : "v"(p2), "v"(p3));
        *(uint2*)(&Ps[w][qh][lm * 72 + mt * 16 + lq * 4]) = pk;
      }
    }
    asm volatile("s_waitcnt lgkmcnt(0)" ::: "memory");

    // O += P V for both q-halves; V fragments read ONCE per (ks,nt).
    __builtin_amdgcn_s_setprio(1);
#pragma unroll
    for (int ks = 0; ks < 2; ++ks) {
      bf16x8 pa0 = *(const bf16x8*)(&Ps[w][0][lm * 72 + ks * 32 + lq * 8]);
      bf16x8 pa1 = *(const bf16x8*)(&Ps[w][1][lm * 72 + ks * 32 + lq * 8]);
#pragma unroll
      for (int nt = 0; nt < 4; ++nt) {
        const unsigned short* vr = Vc + (nt * 16 + lm) * 64;
        bf16x8 vfr = *(const bf16x8*)(vr + (ks == 0 ? c0 : c1));
        oacc[0][nt] = mfma16(pa0, vfr, oacc[0][nt]);
        oacc[1][nt] = mfma16(pa1, vfr, oacc[1][nt]);
      }
      lacc[0] = mfma16(pa0, vones, lacc[0]);
      lacc[1] = mfma16(pa1, vones, lacc[1]);
    }
    __builtin_amdgcn_s_setprio(0);
  }

  // cross-group combine: group 1 parks partials in LDS, group 0 finalizes.
  // lacc[qh][r] holds lsum for q-row qs + qh*16 + lq*4 + r (all lanes).
  __syncthreads();
  float* fbuf = (float*)Ks;  // 64x64 fp32 = 16 KB (Ks block is 16 KB)
  float* lbuf = (float*)Ps;  // 64 fp32, indexed by q-row within tile
  if (g == 1) {
#pragma unroll
    for (int qh = 0; qh < 2; ++qh) {
      const int qq = qs + qh * 16 + lq * 4;
#pragma unroll
      for (int nt = 0; nt < 4; ++nt)
#pragma unroll
        for (int r = 0; r < 4; ++r)
          fbuf[(qq + r) * 64 + nt * 16 + lm] = oacc[qh][nt][r];
      if (lm == 0) {
#pragma unroll
        for (int r = 0; r < 4; ++r) lbuf[qq + r] = lacc[qh][r];
      }
    }
  }
  __syncthreads();
  if (g == 0) {
#pragma unroll
    for (int qh = 0; qh < 2; ++qh) {
      const int qq = qs + qh * 16 + lq * 4;
      float rinv[4];
#pragma unroll
      for (int r = 0; r < 4; ++r)
        rinv[r] = 1.f / (lacc[qh][r] + lbuf[qq + r]);
#pragma unroll
      for (int nt = 0; nt < 4; ++nt)
#pragma unroll
        for (int r = 0; r < 4; ++r) {
          float v = oacc[qh][nt][r] + fbuf[(qq + r) * 64 + nt * 16 + lm];
          size_t tok = (size_t)b * 2048 + ti * 64 + qq + r;
          ctx[tok * 1024 + h * 64 + nt * 16 + lm] = f2b(v * rinv[r]);
        }
    }
  }
}

// ---------------------------------------------------------------- launch
extern "C" void kernel_launch(void* const* d_in, const int* in_sizes, int n_in,
                              void* d_out, int out_size, void* d_ws,
                              size_t ws_size, hipStream_t stream) {
  const float* query = (const float*)d_in[0];
  // d_in[1] key, d_in[2] value: unused by reference. d_in[3] mask: causal
  // tril, applied analytically.
  const float* w_qkv = (const float*)d_in[4];
  const float* w_o = (const float*)d_in[5];
  float* out = (float*)d_out;

  unsigned short* ws = (unsigned short*)d_ws;
  unsigned short* wqkvT = ws;                               // 3072*1024
  unsigned short* woT = wqkvT + (size_t)3072 * 1024;        // 1024*1024
  unsigned short* Xb = woT + (size_t)1024 * 1024;           // 4096*1024
  unsigned short* qkv = Xb + (size_t)4096 * 1024;           // 4096*3072 (Q,K)
  unsigned short* Vt = qkv + (size_t)4096 * 3072;           // 32*64*2048
  unsigned short* ctx = Xb;  // Xb dead after gemm_qkv -> reuse for ctx
  // total: 48 MB of d_ws

  prep<<<dim3(3072), 256, 0, stream>>>(query, w_qkv, w_o, Xb, wqkvT, woT);
  gemm_qkv<<<dim3(24, 32), 256, 0, stream>>>(Xb, wqkvT, qkv, Vt);
  attn_fwd<<<dim3(32, 32), 256, 0, stream>>>(qkv, Vt, ctx);
  gemm_o<<<dim3(8, 32), 256, 0, stream>>>(ctx, woT, out, 4096, 1024, 1024);
}